// Round 1
// baseline (437.222 us; speedup 1.0000x reference)
//
#include <hip/hip_runtime.h>
#include <hip/hip_bf16.h>

typedef __bf16 bf16x8 __attribute__((ext_vector_type(8)));
typedef __bf16 bf16x4v __attribute__((ext_vector_type(4)));
typedef float f32x4 __attribute__((ext_vector_type(4)));

#define MFMA16(a, b, c) __builtin_amdgcn_mfma_f32_16x16x32_bf16((a), (b), (c), 0, 0, 0)

static constexpr int D = 256;
static constexpr float ATTN_SCALE = 0.0625f;  // 256^-0.5

// ---------------- projection GEMM: Y = X @ W^T ----------------
// X: [M, 256] (f32 or bf16 per IN_F32), W: [256,256] f32 row-major (row n = weights of output col n)
// Y: [M, 256] bf16 (or f32 if OUT_F32). TRANS_OUT: write Y^T per batch of 4096 rows: [b][n][m%4096] bf16.
template<bool IN_F32, bool OUT_F32, bool TRANS_OUT>
__global__ __launch_bounds__(256, 2)
void proj_kernel(const void* __restrict__ Xv, const float* __restrict__ W, void* __restrict__ Yv)
{
    __shared__ __bf16 lds_a[128][72];   // [rows][BK=64 + 8 pad]
    __shared__ __bf16 lds_b[128][72];
    const int t = threadIdx.x;
    const int row0 = blockIdx.x * 128;
    const int n0   = blockIdx.y * 128;
    const int lane = t & 63, w = t >> 6;
    const int wr = w >> 1, wc = w & 1;
    const int lr = lane & 15, lg = lane >> 4;

    f32x4 acc[4][4] = {};

    for (int kk = 0; kk < 4; ++kk) {
        __syncthreads();
        if constexpr (IN_F32) {
            const float* X = (const float*)Xv;
            #pragma unroll
            for (int p = 0; p < 8; ++p) {
                int idx4 = p * 256 + t;                 // 2048 float4 chunks (128x64)
                int r = idx4 >> 4, c4 = (idx4 & 15) << 2;
                float4 v4 = *(const float4*)&X[(size_t)(row0 + r) * D + kk * 64 + c4];
                bf16x4v pk = { (__bf16)v4.x, (__bf16)v4.y, (__bf16)v4.z, (__bf16)v4.w };
                *(bf16x4v*)&lds_a[r][c4] = pk;
            }
        } else {
            const __bf16* X = (const __bf16*)Xv;
            #pragma unroll
            for (int p = 0; p < 4; ++p) {
                int idx8 = p * 256 + t;                 // 1024 chunks of 8 bf16
                int r = idx8 >> 3, c8 = (idx8 & 7) << 3;
                *(bf16x8*)&lds_a[r][c8] = *(const bf16x8*)&X[(size_t)(row0 + r) * D + kk * 64 + c8];
            }
        }
        #pragma unroll
        for (int p = 0; p < 8; ++p) {
            int idx4 = p * 256 + t;
            int r = idx4 >> 4, c4 = (idx4 & 15) << 2;
            float4 v4 = *(const float4*)&W[(size_t)(n0 + r) * D + kk * 64 + c4];
            bf16x4v pk = { (__bf16)v4.x, (__bf16)v4.y, (__bf16)v4.z, (__bf16)v4.w };
            *(bf16x4v*)&lds_b[r][c4] = pk;
        }
        __syncthreads();
        #pragma unroll
        for (int ks = 0; ks < 2; ++ks) {
            bf16x8 af[4], bfr[4];
            #pragma unroll
            for (int i = 0; i < 4; ++i) {
                af[i]  = *(bf16x8*)&lds_a[wr * 64 + i * 16 + lr][ks * 32 + 8 * lg];
                bfr[i] = *(bf16x8*)&lds_b[wc * 64 + i * 16 + lr][ks * 32 + 8 * lg];
            }
            #pragma unroll
            for (int i = 0; i < 4; ++i)
                #pragma unroll
                for (int j = 0; j < 4; ++j)
                    acc[i][j] = MFMA16(af[i], bfr[j], acc[i][j]);
        }
    }

    // epilogue — C layout: col = lane&15, row = 4*(lane>>4) + reg
    if constexpr (TRANS_OUT) {
        __bf16* Y = (__bf16*)Yv;
        #pragma unroll
        for (int i = 0; i < 4; ++i) {
            int mbase = row0 + wr * 64 + i * 16 + 4 * lg;   // +r consecutive
            int bb = mbase >> 12, mm = mbase & 4095;
            #pragma unroll
            for (int j = 0; j < 4; ++j) {
                int n = n0 + wc * 64 + j * 16 + lr;
                bf16x4v pk = { (__bf16)acc[i][j][0], (__bf16)acc[i][j][1],
                               (__bf16)acc[i][j][2], (__bf16)acc[i][j][3] };
                *(bf16x4v*)&Y[(((size_t)bb * D + n) << 12) + mm] = pk;
            }
        }
    } else if constexpr (OUT_F32) {
        float* Y = (float*)Yv;
        #pragma unroll
        for (int i = 0; i < 4; ++i)
            #pragma unroll
            for (int j = 0; j < 4; ++j) {
                int n = n0 + wc * 64 + j * 16 + lr;
                #pragma unroll
                for (int r = 0; r < 4; ++r) {
                    int m = row0 + wr * 64 + i * 16 + 4 * lg + r;
                    Y[(size_t)m * D + n] = acc[i][j][r];
                }
            }
    } else {
        __bf16* Y = (__bf16*)Yv;
        #pragma unroll
        for (int i = 0; i < 4; ++i)
            #pragma unroll
            for (int j = 0; j < 4; ++j) {
                int n = n0 + wc * 64 + j * 16 + lr;
                #pragma unroll
                for (int r = 0; r < 4; ++r) {
                    int m = row0 + wr * 64 + i * 16 + 4 * lg + r;
                    Y[(size_t)m * D + n] = (__bf16)acc[i][j][r];
                }
            }
    }
}

// ---------------- flash attention ----------------
// qh: [B*2048, 256] bf16   kh: [B*4096, 256] bf16   vt: [B][256][4096] bf16 (per-batch transposed)
// mask: [B,4096] int (nonzero = keep)   xh out: [B*2048, 256] bf16
// grid: 256 blocks (b = bid&7 -> XCD-locality per batch), 4 waves x 16 q-rows, KV tile = 64 keys
__global__ __launch_bounds__(256, 1)
void attn_kernel(const __bf16* __restrict__ qh, const __bf16* __restrict__ kh,
                 const __bf16* __restrict__ vt, const int* __restrict__ mask,
                 __bf16* __restrict__ xh)
{
    extern __shared__ char smem[];
    __bf16* lds_k  = (__bf16*)smem;                                  // [64][264]
    __bf16* lds_vt = (__bf16*)(smem + 64 * 264 * 2);                 // [256][72]
    __bf16* p_all  = (__bf16*)(smem + 64 * 264 * 2 + 256 * 72 * 2);  // [4][16][72]

    const int t = threadIdx.x, lane = t & 63, w = t >> 6;
    const int lr = lane & 15, lg = lane >> 4;
    const int b = blockIdx.x & 7, qb = blockIdx.x >> 3;
    const int q0 = qb * 64;
    __bf16* myp = p_all + w * (16 * 72);

    // Q fragments in registers (wave owns rows q0 + w*16 .. +16)
    bf16x8 qf[8];
    {
        const size_t qrow = (size_t)b * 2048 + q0 + w * 16 + lr;
        #pragma unroll
        for (int ks = 0; ks < 8; ++ks)
            qf[ks] = *(const bf16x8*)&qh[qrow * D + ks * 32 + 8 * lg];
    }

    f32x4 o[16] = {};
    float mrow[4] = { -1e30f, -1e30f, -1e30f, -1e30f };
    float lrow[4] = { 0.f, 0.f, 0.f, 0.f };

    for (int kt = 0; kt < 64; ++kt) {
        __syncthreads();
        // stage K tile: 64 keys x 256 d
        #pragma unroll
        for (int p = 0; p < 8; ++p) {
            int idx8 = p * 256 + t;
            int r = idx8 >> 5, c8 = (idx8 & 31) << 3;
            *(bf16x8*)&lds_k[r * 264 + c8] =
                *(const bf16x8*)&kh[((size_t)b * 4096 + kt * 64 + r) * D + c8];
        }
        // stage Vt tile: 256 d x 64 keys
        #pragma unroll
        for (int p = 0; p < 8; ++p) {
            int idx8 = p * 256 + t;
            int r = idx8 >> 3, c8 = (idx8 & 7) << 3;
            *(bf16x8*)&lds_vt[r * 72 + c8] =
                *(const bf16x8*)&vt[(((size_t)b * D + r) << 12) + kt * 64 + c8];
        }
        float madd[4];
        #pragma unroll
        for (int ct = 0; ct < 4; ++ct)
            madd[ct] = mask[b * 4096 + kt * 64 + ct * 16 + lr] ? 0.0f : -10000.0f;
        __syncthreads();

        // S = Q K^T  (16 rows x 64 keys per wave)
        f32x4 s[4] = {};
        #pragma unroll
        for (int ct = 0; ct < 4; ++ct) {
            #pragma unroll
            for (int ks = 0; ks < 8; ++ks) {
                bf16x8 kf = *(bf16x8*)&lds_k[(ct * 16 + lr) * 264 + ks * 32 + 8 * lg];
                s[ct] = MFMA16(qf[ks], kf, s[ct]);
            }
        }

        // online softmax: row = 4*lg + r spread across 16 lanes (l&15) x 4 col-tiles
        #pragma unroll
        for (int r = 0; r < 4; ++r) {
            float sv[4];
            #pragma unroll
            for (int ct = 0; ct < 4; ++ct) sv[ct] = s[ct][r] * ATTN_SCALE + madd[ct];
            float mx = fmaxf(fmaxf(sv[0], sv[1]), fmaxf(sv[2], sv[3]));
            mx = fmaxf(mx, __shfl_xor(mx, 1));
            mx = fmaxf(mx, __shfl_xor(mx, 2));
            mx = fmaxf(mx, __shfl_xor(mx, 4));
            mx = fmaxf(mx, __shfl_xor(mx, 8));
            float mnew = fmaxf(mrow[r], mx);
            float alpha = __expf(mrow[r] - mnew);
            mrow[r] = mnew;
            float ps = 0.f;
            int qlocal = 4 * lg + r;
            #pragma unroll
            for (int ct = 0; ct < 4; ++ct) {
                float pv = __expf(sv[ct] - mnew);
                ps += pv;
                myp[qlocal * 72 + ct * 16 + lr] = (__bf16)pv;   // P^T bounce via LDS
            }
            ps += __shfl_xor(ps, 1);
            ps += __shfl_xor(ps, 2);
            ps += __shfl_xor(ps, 4);
            ps += __shfl_xor(ps, 8);
            lrow[r] = lrow[r] * alpha + ps;
            #pragma unroll
            for (int dt = 0; dt < 16; ++dt) o[dt][r] *= alpha;
        }

        // PV: O += P[16x64] * V[64x256]
        bf16x8 pa[2];
        #pragma unroll
        for (int ks2 = 0; ks2 < 2; ++ks2)
            pa[ks2] = *(bf16x8*)&myp[lr * 72 + ks2 * 32 + 8 * lg];
        #pragma unroll
        for (int dt = 0; dt < 16; ++dt) {
            #pragma unroll
            for (int ks2 = 0; ks2 < 2; ++ks2) {
                bf16x8 vb = *(bf16x8*)&lds_vt[(dt * 16 + lr) * 72 + ks2 * 32 + 8 * lg];
                o[dt] = MFMA16(pa[ks2], vb, o[dt]);
            }
        }
    }

    // epilogue: normalize, write xh bf16
    #pragma unroll
    for (int r = 0; r < 4; ++r) {
        float inv = 1.0f / lrow[r];
        size_t qg = (size_t)b * 2048 + q0 + w * 16 + 4 * lg + r;
        #pragma unroll
        for (int dt = 0; dt < 16; ++dt)
            xh[qg * D + dt * 16 + lr] = (__bf16)(o[dt][r] * inv);
    }
}

extern "C" void kernel_launch(void* const* d_in, const int* in_sizes, int n_in,
                              void* d_out, int out_size, void* d_ws, size_t ws_size,
                              hipStream_t stream)
{
    const float* q  = (const float*)d_in[0];
    const float* k  = (const float*)d_in[1];
    const float* v  = (const float*)d_in[2];
    const int* mask = (const int*)d_in[3];
    const float* Wq = (const float*)d_in[4];
    const float* Wk = (const float*)d_in[5];
    const float* Wv = (const float*)d_in[6];
    const float* Wp = (const float*)d_in[7];
    float* out = (float*)d_out;

    __bf16* qh = (__bf16*)d_ws;                       //  8 MB  [16384][256]
    __bf16* kh = qh + (size_t)16384 * 256;            // 16 MB  [32768][256]
    __bf16* vt = kh + (size_t)32768 * 256;            // 16 MB  [8][256][4096]
    __bf16* xh = vt + (size_t)32768 * 256;            //  8 MB  [16384][256]

    // projections (q/k row counts: 16384 / 32768; all M % 128 == 0, batches % 128 == 0)
    proj_kernel<true, false, false><<<dim3(128, 2), 256, 0, stream>>>((const void*)q, Wq, (void*)qh);
    proj_kernel<true, false, false><<<dim3(256, 2), 256, 0, stream>>>((const void*)k, Wk, (void*)kh);
    proj_kernel<true, false, true ><<<dim3(256, 2), 256, 0, stream>>>((const void*)v, Wv, (void*)vt);

    constexpr int attn_lds = 64 * 264 * 2 + 256 * 72 * 2 + 4 * 16 * 72 * 2;  // 79872 B
    hipFuncSetAttribute((const void*)attn_kernel, hipFuncAttributeMaxDynamicSharedMemorySize, attn_lds);
    attn_kernel<<<256, 256, attn_lds, stream>>>(qh, kh, vt, mask, xh);

    proj_kernel<false, true, false><<<dim3(128, 2), 256, 0, stream>>>((const void*)xh, Wp, (void*)out);
}